// Round 3
// baseline (632.461 us; speedup 1.0000x reference)
//
#include <hip/hip_runtime.h>
#include <cstdint>

#define AS1 __attribute__((address_space(1)))
#define AS3 __attribute__((address_space(3)))

typedef __attribute__((ext_vector_type(8))) short short8;
typedef __attribute__((ext_vector_type(4))) float floatx4;
typedef unsigned short u16;

static constexpr int NN   = 100000;
static constexpr int FF   = 512;
static constexpr int HH   = 128;
static constexpr int EE   = 1600000;
static constexpr int PADM = 100096;   // 3128 * 32
static constexpr int NPAD = 100352;   // 98 * 1024
static constexpr int NB   = 98;

__device__ __forceinline__ u16 f2bf_rne(float v) {
    uint32_t u = __builtin_bit_cast(uint32_t, v);
    u += 0x7fffu + ((u >> 16) & 1u);
    return (u16)(u >> 16);
}
__device__ __forceinline__ float bf2f(u16 h) {
    uint32_t u = ((uint32_t)h) << 16;
    return __builtin_bit_cast(float, u);
}
__device__ __forceinline__ void async16(const void* g, void* l) {
    __builtin_amdgcn_global_load_lds((AS1 const void*)g, (AS3 void*)l, 16, 0, 0);
}

// ---- W1^T = [Wm1|Ws1]^T as bf16 hi/lo, layout [n=256][k=512] ---------------
__global__ void k_split_w(const float* __restrict__ Wm1, const float* __restrict__ Ws1,
                          u16* __restrict__ whi, u16* __restrict__ wlo) {
    int t = blockIdx.x * 256 + threadIdx.x;           // t < 256*512
    int n = t >> 9, k = t & 511;
    float v = (n < HH) ? Wm1[k * HH + n] : Ws1[k * HH + (n - HH)];
    u16 h = f2bf_rne(v);
    whi[t] = h;
    wlo[t] = f2bf_rne(v - bf2f(h));
}

// ---- W2 MFMA B-fragments: plane 0 = Wm2-hi, 1 = Ws2-hi, 2 = Ws2-lo ---------
__global__ void k_prep_w2(const float* __restrict__ Wm2, const float* __restrict__ Ws2,
                          u16* __restrict__ W2B) {
    int t = blockIdx.x * 256 + threadIdx.x;           // t < 6144
    int j = t & 7, l = (t >> 3) & 63, kc = (t >> 9) & 3, p = t >> 11;
    int n = l & 15, quad = l >> 4;
    int k = kc * 32 + quad * 8 + j;
    float v = 0.f;
    if (n < 8) {
        float wv = (p == 0) ? Wm2[k * 8 + n] : Ws2[k * 8 + n];
        v = (p == 2) ? (wv - bf2f(f2bf_rne(wv))) : wv;
    }
    W2B[t] = f2bf_rne(v);
}

// ---- degree / d_half / d_one -----------------------------------------------
__global__ void k_deg(const int* __restrict__ dst, int* __restrict__ deg) {
    int e = blockIdx.x * 256 + threadIdx.x;
    atomicAdd(&deg[dst[e]], 1);
}
__global__ void k_dh(const int* __restrict__ deg, float2* __restrict__ dd) {
    int t = blockIdx.x * 256 + threadIdx.x;           // t < NPAD
    int d = max(deg[t], 1);
    float df = (float)d;
    dd[t] = make_float2(1.f / sqrtf(df), 1.f / df);
}

// ---- fused GEMM1 + activations + GEMM2 -> Z[node][16] ----------------------
// Re-tiled for TLP: block = 32 rows x 256 cols, 256 threads / 4 waves.
// Per-wave acc = 8 tiles (32 AGPR) + ~55 VGPR -> ~90 total regs -> 5 waves/EU;
// LDS 28 KB -> 5 blocks/CU => ~20 resident waves/CU (was 16 at 128 regs).
// All 4 waves share the 32 A-rows; wave w owns cols 32*w (miu) + 32*w (sigma).
// Quad-XOR swizzle retained (keys reduce to xq=(ml>>1)&3 for A and B).
__global__ __launch_bounds__(256, 5) void k_gemm(
        const float* __restrict__ A,
        const u16* __restrict__ BhiG, const u16* __restrict__ BloG,
        const u16* __restrict__ W2B, const float2* __restrict__ dd,
        float* __restrict__ Z) {
    __shared__ u16 sm[14336];   // 28 KB
    // K-loop: Ahi[0,1024) Alo[1024,2048) Bmh[2048,6144) Bsh[6144,10240) Bsl[10240,14336)
    // epi:    xm[0,4352)  xs_hi[4352,8704)  xs_lo[8704,13056)  (stride 136)
    const int tid = threadIdx.x;
    const int w = tid >> 6, lane = tid & 63;
    const int ml = lane & 15, quad = lane >> 4;
    const int wcol = w;                               // 4 col-groups of 32
    const int rowBase = blockIdx.x * 32;

    floatx4 am[2][2], as_[2][2];
#pragma unroll
    for (int i = 0; i < 2; i++)
#pragma unroll
        for (int j = 0; j < 2; j++) {
            am[i][j]  = (floatx4){0.f, 0.f, 0.f, 0.f};
            as_[i][j] = (floatx4){0.f, 0.f, 0.f, 0.f};
        }

    // B staging: 256 threads x 6 async16 (2 chunks per region).
    const int r0 = tid >> 2, q0 = tid & 3;            // r0: 0..63
    const int key0 = (r0 >> 1) & 3;
    const int kob = (q0 ^ key0) * 8;                  // pre-swizzled source chunk
    const u16* gBh = BhiG + (size_t)r0 * FF + kob;          // miu rows 0..63 (+64*FF for 64..127)
    const u16* gBl = BloG + (size_t)(128 + r0) * FF + kob;  // sigma-lo rows 128..191 (+64*FF)

    // A staging: threads 0..127 only (32 rows x 32 k = 1024 f32, 8 f32/thread).
    const int ar = tid >> 2, aq = tid & 3;            // ar: 0..63 (use <32 via tid<128)
    const int akey = (ar >> 1) & 3;
    const int arow = min(rowBase + ar, NN - 1);       // clamp; pad rows discarded
    const float* gA = A + (size_t)arow * FF + aq * 8;
    const int awr = ar * 32 + (aq ^ akey) * 8;        // A ds_write slot (u16), <1024

    const int xq = (ml >> 1) & 3;                     // read-side swizzle key
    const int qx = (quad ^ xq) * 8;
    const int aoff = ml * 32 + qx;                    // + i*512 (rows i*16+ml)
    const int bmo  = 2048  + (32 * wcol + ml) * 32 + qx;   // + jm*512
    const int bso  = 6144  + (32 * wcol + ml) * 32 + qx;
    const int blo_ = 10240 + (32 * wcol + ml) * 32 + qx;

    for (int kt = 0; kt < FF; kt += 32) {
        __syncthreads();
        async16(gBh + kt,                      &sm[2048  + tid * 8]);
        async16(gBh + (size_t)64  * FF + kt,   &sm[4096  + tid * 8]);
        async16(gBh + (size_t)128 * FF + kt,   &sm[6144  + tid * 8]);
        async16(gBh + (size_t)192 * FF + kt,   &sm[8192  + tid * 8]);
        async16(gBl + kt,                      &sm[10240 + tid * 8]);
        async16(gBl + (size_t)64  * FF + kt,   &sm[12288 + tid * 8]);
        if (tid < 128) {
            const float4* pA = (const float4*)(gA + kt);
            float4 x0 = pA[0], x1 = pA[1];
            float xv[8] = {x0.x, x0.y, x0.z, x0.w, x1.x, x1.y, x1.z, x1.w};
            short8 hv, lv;
#pragma unroll
            for (int q = 0; q < 8; q++) {
                u16 hh = f2bf_rne(xv[q]);
                hv[q] = (short)hh;
                lv[q] = (short)f2bf_rne(xv[q] - bf2f(hh));
            }
            *(short8*)&sm[awr] = hv;
            *(short8*)&sm[1024 + awr] = lv;
        }
        __syncthreads();

        short8 ah[2], al[2];
#pragma unroll
        for (int i = 0; i < 2; i++) ah[i] = *(const short8*)&sm[aoff + i * 512];
#pragma unroll
        for (int i = 0; i < 2; i++) al[i] = *(const short8*)&sm[1024 + aoff + i * 512];
#pragma unroll
        for (int jm = 0; jm < 2; jm++) {
            short8 b = *(const short8*)&sm[bmo + jm * 512];
#pragma unroll
            for (int i = 0; i < 2; i++)
                am[i][jm] = __builtin_amdgcn_mfma_f32_16x16x32_bf16(ah[i], b, am[i][jm], 0, 0, 0);
        }
#pragma unroll
        for (int js = 0; js < 2; js++) {
            short8 bh = *(const short8*)&sm[bso + js * 512];
            short8 bl = *(const short8*)&sm[blo_ + js * 512];
#pragma unroll
            for (int i = 0; i < 2; i++) {
                floatx4 c = as_[i][js];
                c = __builtin_amdgcn_mfma_f32_16x16x32_bf16(ah[i], bh, c, 0, 0, 0);
                c = __builtin_amdgcn_mfma_f32_16x16x32_bf16(ah[i], bl, c, 0, 0, 0);
                c = __builtin_amdgcn_mfma_f32_16x16x32_bf16(al[i], bh, c, 0, 0, 0);
                as_[i][js] = c;
            }
        }
    }

    // ---- epilogue: single 32-row chunk -------------------------------------
    short8 wm[4], wsh[4], wsl[4];
#pragma unroll
    for (int kc = 0; kc < 4; kc++) {
        wm[kc]  = *(const short8*)&W2B[(kc * 64 + lane) * 8];
        wsh[kc] = *(const short8*)&W2B[2048 + (kc * 64 + lane) * 8];
        wsl[kc] = *(const short8*)&W2B[4096 + (kc * 64 + lane) * 8];
    }
    const int rg = w & 1, pp = w >> 1;

    __syncthreads();
    // producers: every wave writes its 32-col slice for all 32 rows
#pragma unroll
    for (int i = 0; i < 2; i++) {
#pragma unroll
        for (int jm = 0; jm < 2; jm++) {
            int c = 32 * wcol + 16 * jm + ml;
#pragma unroll
            for (int r = 0; r < 4; r++) {
                int lr = i * 16 + quad * 4 + r;          // 0..31
                float2 d2 = dd[rowBase + lr];            // < NPAD
                float u = am[i][jm][r], v = as_[i][jm][r];
                float m1 = u > 0.f ? u : __expf(u) - 1.f;
                float s1 = v > 0.f ? v : 0.f;
                float a1 = __expf(-s1);
                float xmv = d2.x * m1 * a1;
                float xsv = d2.y * s1 * a1 * a1;
                u16 hh = f2bf_rne(xsv);
                sm[lr * 136 + c]        = f2bf_rne(xmv);
                sm[4352 + lr * 136 + c] = hh;
                sm[8704 + lr * 136 + c] = f2bf_rne(xsv - bf2f(hh));
            }
        }
    }
    __syncthreads();
    // consumers: 4 waves, rg = row half, pp = plane (miu / sigma)
    {
        floatx4 z = (floatx4){0.f, 0.f, 0.f, 0.f};
#pragma unroll
        for (int kc = 0; kc < 4; kc++) {
            if (pp == 0) {
                short8 a = *(const short8*)&sm[(rg * 16 + ml) * 136 + kc * 32 + quad * 8];
                z = __builtin_amdgcn_mfma_f32_16x16x32_bf16(a, wm[kc], z, 0, 0, 0);
            } else {
                short8 a = *(const short8*)&sm[4352 + (rg * 16 + ml) * 136 + kc * 32 + quad * 8];
                short8 b = *(const short8*)&sm[8704 + (rg * 16 + ml) * 136 + kc * 32 + quad * 8];
                z = __builtin_amdgcn_mfma_f32_16x16x32_bf16(a, wsh[kc], z, 0, 0, 0);
                z = __builtin_amdgcn_mfma_f32_16x16x32_bf16(a, wsl[kc], z, 0, 0, 0);
                z = __builtin_amdgcn_mfma_f32_16x16x32_bf16(b, wsh[kc], z, 0, 0, 0);
            }
        }
        if (ml < 8) {
            int rowb = rowBase + rg * 16 + quad * 4;
#pragma unroll
            for (int r = 0; r < 4; r++)
                if (rowb + r < NN) Z[(size_t)(rowb + r) * 16 + pp * 8 + ml] = z[r];
        }
    }
}

// ================= CSR build =================================================
__global__ void k_scan1(const int* __restrict__ deg, int* __restrict__ bsum) {
    int t = threadIdx.x;
    int4 v = ((const int4*)deg)[blockIdx.x * 256 + t];
    __shared__ int red[256];
    red[t] = v.x + v.y + v.z + v.w;
    __syncthreads();
    for (int o = 128; o > 0; o >>= 1) {
        if (t < o) red[t] += red[t + o];
        __syncthreads();
    }
    if (t == 0) bsum[blockIdx.x] = red[0];
}

__global__ void k_scan2(const int* __restrict__ bsum, int* __restrict__ boff) {
    int t = threadIdx.x;                       // 128 threads
    __shared__ int s[128];
    int own = (t < NB) ? bsum[t] : 0;
    s[t] = own;
    __syncthreads();
    for (int o = 1; o < 128; o <<= 1) {
        int v = (t >= o) ? s[t - o] : 0;
        __syncthreads();
        s[t] += v;
        __syncthreads();
    }
    if (t < NB) boff[t] = s[t] - own;          // exclusive
}

__global__ void k_scan3(const int* __restrict__ deg, const int* __restrict__ boff,
                        int* __restrict__ ptr, int* __restrict__ cursor) {
    int t = threadIdx.x;
    int gi = blockIdx.x * 256 + t;
    int4 v = ((const int4*)deg)[gi];
    int tsum = v.x + v.y + v.z + v.w;
    __shared__ int s[256];
    s[t] = tsum;
    __syncthreads();
    for (int o = 1; o < 256; o <<= 1) {
        int pv = (t >= o) ? s[t - o] : 0;
        __syncthreads();
        s[t] += pv;
        __syncthreads();
    }
    int base = boff[blockIdx.x] + (s[t] - tsum);
    int4 e;
    e.x = base;
    e.y = base + v.x;
    e.z = e.y + v.y;
    e.w = e.z + v.z;
    ((int4*)ptr)[gi] = e;
    ((int4*)cursor)[gi] = e;
}

// payload = src index only (4 B); prime-read keeps the line in L2 so the
// random store is a write-hit instead of a 64B dirty-line HBM flush.
__global__ void k_scatter(const int* __restrict__ src, const int* __restrict__ dst,
                          int* __restrict__ cursor, int* __restrict__ pay) {
    int e = blockIdx.x * 256 + threadIdx.x;
    int d = dst[e];
    int p = atomicAdd(&cursor[d], 1);
    int pr = pay[p];                            // prime line into L2
    asm volatile("" :: "v"(pr) : "memory");     // keep load + ordering
    pay[p] = src[e];
}

// ---- agg1 + node transform fused -------------------------------------------
// wave per node i: hm = dh*sum Z[s][c], hs = dinv*sum Z[s][8+c];
// y[i] = dh[i]*elu(hm)*exp(-relu(hs)); out[i] = noise*sqrt(relu(hs)+eps)
__global__ __launch_bounds__(256) void k_aggA(const int* __restrict__ ptr,
        const int* __restrict__ pay, const float* __restrict__ Z,
        const float2* __restrict__ dd, const float* __restrict__ noise,
        float* __restrict__ y, float* __restrict__ out) {
    int wave = threadIdx.x >> 6, lane = threadIdx.x & 63;
    int i = blockIdx.x * 4 + wave;
    if (i >= NN) return;
    int er = lane >> 3, c = lane & 7;
    int s0 = ptr[i], e0 = ptr[i + 1];
    float am = 0.f, as_ = 0.f;
    int j = s0 + er;
    int sidx = (j < e0) ? pay[j] : -1;
    while (sidx >= 0) {                         // pipelined: next pay in flight
        int jn = j + 8;
        int snext = (jn < e0) ? pay[jn] : -1;
        const float* zr = Z + (size_t)sidx * 16;
        am  += zr[c];
        as_ += zr[8 + c];
        j = jn;
        sidx = snext;
    }
    am  += __shfl_xor(am, 8, 64);
    am  += __shfl_xor(am, 16, 64);
    am  += __shfl_xor(am, 32, 64);
    as_ += __shfl_xor(as_, 8, 64);
    as_ += __shfl_xor(as_, 16, 64);
    as_ += __shfl_xor(as_, 32, 64);
    if (lane < 8) {
        float2 d2 = dd[i];
        float hm = d2.x * am, hs = d2.y * as_;
        float miu2 = hm > 0.f ? hm : __expf(hm) - 1.f;
        float s2 = hs > 0.f ? hs : 0.f;
        y[i * 8 + lane]   = d2.x * miu2 * __expf(-s2);   // dh[src] folded in
        out[i * 8 + lane] = noise[i * 8 + lane] * sqrtf(s2 + 1e-8f);
    }
}

// ---- agg2: out[i][c] += dh[i] * sum y[s][c] --------------------------------
__global__ __launch_bounds__(256) void k_aggB(const int* __restrict__ ptr,
        const int* __restrict__ pay, const float* __restrict__ y,
        const float2* __restrict__ dd, float* __restrict__ out) {
    int wave = threadIdx.x >> 6, lane = threadIdx.x & 63;
    int i = blockIdx.x * 4 + wave;
    if (i >= NN) return;
    int er = lane >> 3, c = lane & 7;
    int s0 = ptr[i], e0 = ptr[i + 1];
    float acc = 0.f;
    int j = s0 + er;
    int sidx = (j < e0) ? pay[j] : -1;
    while (sidx >= 0) {
        int jn = j + 8;
        int snext = (jn < e0) ? pay[jn] : -1;
        acc += y[(size_t)sidx * 8 + c];
        j = jn;
        sidx = snext;
    }
    acc += __shfl_xor(acc, 8, 64);
    acc += __shfl_xor(acc, 16, 64);
    acc += __shfl_xor(acc, 32, 64);
    if (lane < 8) out[i * 8 + lane] += dd[i].x * acc;
}

extern "C" void kernel_launch(void* const* d_in, const int* in_sizes, int n_in,
                              void* d_out, int out_size, void* d_ws, size_t ws_size,
                              hipStream_t stream) {
    (void)in_sizes; (void)n_in; (void)out_size; (void)ws_size;
    const float* feat  = (const float*)d_in[0];
    const int*   esrc  = (const int*)d_in[1];
    const int*   edst  = (const int*)d_in[2];
    // d_in[3] (w1), d_in[4] (w2) unused: reconstructed from degrees
    const float* Wm1   = (const float*)d_in[5];
    const float* Ws1   = (const float*)d_in[6];
    const float* Wm2   = (const float*)d_in[7];
    const float* Ws2   = (const float*)d_in[8];
    const float* noise = (const float*)d_in[9];
    float* out = (float*)d_out;

    char* ws = (char*)d_ws;
    size_t off = 0;
    auto alloc = [&](size_t bytes) -> void* {
        void* p = ws + off;
        off += (bytes + 255) & ~(size_t)255;
        return p;
    };
    u16*    WhiT = (u16*)alloc((size_t)256 * 512 * 2);
    u16*    WloT = (u16*)alloc((size_t)256 * 512 * 2);
    u16*    W2B  = (u16*)alloc((size_t)6144 * 2);
    float*  Z    = (float*)alloc((size_t)NN * 16 * 4);
    float*  yb   = (float*)alloc((size_t)NN * 8 * 4);
    int*    deg  = (int*)alloc((size_t)NPAD * 4);
    float2* dd   = (float2*)alloc((size_t)NPAD * 8);
    int*    ptr  = (int*)alloc((size_t)(NPAD + 4) * 4);
    int*    cur  = (int*)alloc((size_t)NPAD * 4);
    int*    bsum = (int*)alloc(256 * 4);
    int*    boff = (int*)alloc(256 * 4);
    int*    pay  = (int*)alloc((size_t)EE * 4);

    hipMemsetAsync(deg, 0, (size_t)NPAD * 4, stream);

    // CSR build + degree weights
    k_deg    <<<EE / 256, 256, 0, stream>>>(edst, deg);
    k_dh     <<<NPAD / 256, 256, 0, stream>>>(deg, dd);
    k_scan1  <<<NB, 256, 0, stream>>>(deg, bsum);
    k_scan2  <<<1, 128, 0, stream>>>(bsum, boff);
    k_scan3  <<<NB, 256, 0, stream>>>(deg, boff, ptr, cur);
    k_scatter<<<EE / 256, 256, 0, stream>>>(esrc, edst, cur, pay);

    // dense pipeline (fused: A-split in-loop, activations + GEMM2 epilogue)
    k_split_w<<<512, 256, 0, stream>>>(Wm1, Ws1, WhiT, WloT);
    k_prep_w2<<<24, 256, 0, stream>>>(Wm2, Ws2, W2B);
    k_gemm   <<<PADM / 32, 256, 0, stream>>>(feat, WhiT, WloT, W2B, dd, Z);

    // aggregation, atomic-free (node transform fused into aggA)
    k_aggA<<<(NN + 3) / 4, 256, 0, stream>>>(ptr, pay, Z, dd, noise, yb, out);
    k_aggB<<<(NN + 3) / 4, 256, 0, stream>>>(ptr, pay, yb, dd, out);
}

// Round 4
// 612.489 us; speedup vs baseline: 1.0326x; 1.0326x over previous
//
#include <hip/hip_runtime.h>
#include <cstdint>

#define AS1 __attribute__((address_space(1)))
#define AS3 __attribute__((address_space(3)))

typedef __attribute__((ext_vector_type(8))) short short8;
typedef __attribute__((ext_vector_type(4))) float floatx4;
typedef unsigned short u16;

static constexpr int NN   = 100000;
static constexpr int FF   = 512;
static constexpr int HH   = 128;
static constexpr int EE   = 1600000;
static constexpr int PADM = 100096;   // 782 * 128
static constexpr int NPAD = 100352;   // 98 * 1024
static constexpr int NB   = 98;

__device__ __forceinline__ u16 f2bf_rne(float v) {
    uint32_t u = __builtin_bit_cast(uint32_t, v);
    u += 0x7fffu + ((u >> 16) & 1u);
    return (u16)(u >> 16);
}
__device__ __forceinline__ float bf2f(u16 h) {
    uint32_t u = ((uint32_t)h) << 16;
    return __builtin_bit_cast(float, u);
}
__device__ __forceinline__ void async16(const void* g, void* l) {
    __builtin_amdgcn_global_load_lds((AS1 const void*)g, (AS3 void*)l, 16, 0, 0);
}

// ---- W1^T = [Wm1|Ws1]^T as bf16 hi/lo, layout [n=256][k=512] ---------------
__global__ void k_split_w(const float* __restrict__ Wm1, const float* __restrict__ Ws1,
                          u16* __restrict__ whi, u16* __restrict__ wlo) {
    int t = blockIdx.x * 256 + threadIdx.x;           // t < 256*512
    int n = t >> 9, k = t & 511;
    float v = (n < HH) ? Wm1[k * HH + n] : Ws1[k * HH + (n - HH)];
    u16 h = f2bf_rne(v);
    whi[t] = h;
    wlo[t] = f2bf_rne(v - bf2f(h));
}

// ---- W2 MFMA B-fragments: plane 0 = Wm2-hi, 1 = Ws2-hi, 2 = Ws2-lo ---------
__global__ void k_prep_w2(const float* __restrict__ Wm2, const float* __restrict__ Ws2,
                          u16* __restrict__ W2B) {
    int t = blockIdx.x * 256 + threadIdx.x;           // t < 6144
    int j = t & 7, l = (t >> 3) & 63, kc = (t >> 9) & 3, p = t >> 11;
    int n = l & 15, quad = l >> 4;
    int k = kc * 32 + quad * 8 + j;
    float v = 0.f;
    if (n < 8) {
        float wv = (p == 0) ? Wm2[k * 8 + n] : Ws2[k * 8 + n];
        v = (p == 2) ? (wv - bf2f(f2bf_rne(wv))) : wv;
    }
    W2B[t] = f2bf_rne(v);
}

// ---- degree / d_half / d_one -----------------------------------------------
__global__ void k_deg(const int* __restrict__ dst, int* __restrict__ deg) {
    int e = blockIdx.x * 256 + threadIdx.x;
    atomicAdd(&deg[dst[e]], 1);
}
__global__ void k_dh(const int* __restrict__ deg, float2* __restrict__ dd) {
    int t = blockIdx.x * 256 + threadIdx.x;           // t < NPAD
    int d = max(deg[t], 1);
    float df = (float)d;
    dd[t] = make_float2(1.f / sqrtf(df), 1.f / df);
}

// ---- fused GEMM1 + activations + GEMM2 -> Z[node][16] ----------------------
// block = 128 rows x 256 cols, 512 threads / 8 waves (round-2 tiling).
// T3 minimum-2-phase pipeline: ALL staging is async global_load_lds (A staged
// as raw f32, bf16 hi/lo split done at fragment-read time where it overlaps
// MFMA on the VALU pipe).  Per step: issue stage(t+1) -> compute(t) ->
// vmcnt(0)+lgkmcnt(0) + raw s_barrier (ONE barrier/step; __syncthreads would
// force an early drain).  DMA latency hides under the compute phase.
// A f32 tile: 128 rows x 128 B; 16B chunks XOR-swizzled with key=row&7
// (source pre-swizzled within the row's 128B line so the linear LDS dest of
// global_load_lds is honored); read lands 2 lanes/bank = free.
__global__ __launch_bounds__(512, 4) void k_gemm(
        const float* __restrict__ A,
        const u16* __restrict__ BhiG, const u16* __restrict__ BloG,
        const u16* __restrict__ W2B, const float2* __restrict__ dd,
        float* __restrict__ Z) {
    __shared__ u16 sm[40960];   // 80 KB: 2 buffers x 20480 u16
    // per buffer (u16 idx): Af32[0,8192) Bmh[8192,12288) Bsh[12288,16384) Bsl[16384,20480)
    // epilogue reuses [0,13056): xm / xs_hi / xs_lo (stride 136)
    const int tid = threadIdx.x;
    const int w = tid >> 6, lane = tid & 63;
    const int ml = lane & 15, quad = lane >> 4;
    const int wrow = w & 1, wcol = w >> 1;
    const int rowBase = blockIdx.x * 128;

    floatx4 am[4][2], as_[4][2];
#pragma unroll
    for (int i = 0; i < 4; i++)
#pragma unroll
        for (int j = 0; j < 2; j++) {
            am[i][j]  = (floatx4){0.f, 0.f, 0.f, 0.f};
            as_[i][j] = (floatx4){0.f, 0.f, 0.f, 0.f};
        }

    // A staging: 1024 16B-chunks/step; thread t stages chunk t (rows 0..63)
    // and chunk 512+t (rows 64..127).  Within-row source chunk g is
    // pre-swizzled: LDS slot (row, cs) holds global chunk cs ^ (row&7).
    const int strow = tid >> 3;                        // 0..63
    const int g = (tid & 7) ^ (strow & 7);
    const int arow1 = min(rowBase + strow, NN - 1);
    const int arow2 = min(rowBase + 64 + strow, NN - 1);
    const float* gA1 = A + (size_t)arow1 * FF + g * 4;
    const float* gA2 = A + (size_t)arow2 * FF + g * 4;

    // B staging: as round 2 (16B-quad swizzle, key (r0>>1)&3, pre-swizzled src)
    const int r0 = tid >> 2, q0 = tid & 3;
    const int key0 = (r0 >> 1) & 3;
    const int kob = (q0 ^ key0) * 8;
    const u16* gBh = BhiG + (size_t)r0 * FF + kob;          // rows 0..127 (hi)
    const u16* gBl = BloG + (size_t)(128 + r0) * FF + kob;  // sigma rows 128..255 (lo)

    // read-side offsets
    const int xq = (ml >> 1) & 3;
    const int bmo  = 8192  + (32 * wcol + ml) * 32 + (quad ^ xq) * 8;
    const int bso  = 12288 + (32 * wcol + ml) * 32 + (quad ^ xq) * 8;
    const int blo_ = 16384 + (32 * wcol + ml) * 32 + (quad ^ xq) * 8;
    const int akey = ml & 7;

    auto stage = [&](int bb, int kt) {
        async16(gA1 + kt, &sm[bb + tid * 8]);
        async16(gA2 + kt, &sm[bb + 4096 + tid * 8]);
        async16(gBh + kt,                      &sm[bb + 8192  + tid * 8]);
        async16(gBh + (size_t)128 * FF + kt,   &sm[bb + 12288 + tid * 8]);
        async16(gBl + kt,                      &sm[bb + 16384 + tid * 8]);
    };

    auto compute = [&](int cb) {
        short8 bm[2], bh[2], bl[2];
#pragma unroll
        for (int jj = 0; jj < 2; jj++) {
            bm[jj] = *(const short8*)&sm[cb + bmo  + jj * 512];
            bh[jj] = *(const short8*)&sm[cb + bso  + jj * 512];
            bl[jj] = *(const short8*)&sm[cb + blo_ + jj * 512];
        }
        const float4* af = (const float4*)&sm[cb];
#pragma unroll
        for (int i = 0; i < 4; i++) {
            int row = wrow * 64 + i * 16 + ml;
            float4 f0 = af[row * 8 + ((quad * 2 + 0) ^ akey)];
            float4 f1 = af[row * 8 + ((quad * 2 + 1) ^ akey)];
            float xv[8] = {f0.x, f0.y, f0.z, f0.w, f1.x, f1.y, f1.z, f1.w};
            short8 ah, al;
#pragma unroll
            for (int q = 0; q < 8; q++) {
                uint32_t u = __builtin_bit_cast(uint32_t, xv[q]);
                uint32_t uh = (u + 0x8000u) & 0xffff0000u;      // hi: round-half-up
                ah[q] = (short)(uh >> 16);
                float lof = xv[q] - __builtin_bit_cast(float, uh);
                al[q] = (short)(__builtin_bit_cast(uint32_t, lof) >> 16);  // lo: trunc
            }
            am[i][0] = __builtin_amdgcn_mfma_f32_16x16x32_bf16(ah, bm[0], am[i][0], 0, 0, 0);
            am[i][1] = __builtin_amdgcn_mfma_f32_16x16x32_bf16(ah, bm[1], am[i][1], 0, 0, 0);
#pragma unroll
            for (int js = 0; js < 2; js++) {
                floatx4 c = as_[i][js];
                c = __builtin_amdgcn_mfma_f32_16x16x32_bf16(ah, bh[js], c, 0, 0, 0);
                c = __builtin_amdgcn_mfma_f32_16x16x32_bf16(ah, bl[js], c, 0, 0, 0);
                c = __builtin_amdgcn_mfma_f32_16x16x32_bf16(al, bh[js], c, 0, 0, 0);
                as_[i][js] = c;
            }
        }
    };

    // prologue: stage tile 0 into buffer 0, wait, sync
    stage(0, 0);
    asm volatile("s_waitcnt vmcnt(0)" ::: "memory");
    __builtin_amdgcn_s_barrier();
    asm volatile("" ::: "memory");

    int cur = 0;
    for (int kt = 0; kt < FF; kt += 32) {
        if (kt + 32 < FF) stage((cur ^ 1) * 20480, kt + 32);  // issue t+1 first
        compute(cur * 20480);                                  // overlaps DMA
        asm volatile("s_waitcnt vmcnt(0) lgkmcnt(0)" ::: "memory");
        __builtin_amdgcn_s_barrier();
        asm volatile("" ::: "memory");
        cur ^= 1;
    }

    // ---- epilogue: 4 chunks of 32 rows -------------------------------------
    short8 wm[4], wsh[4], wsl[4];
#pragma unroll
    for (int kc = 0; kc < 4; kc++) {
        wm[kc]  = *(const short8*)&W2B[(kc * 64 + lane) * 8];
        wsh[kc] = *(const short8*)&W2B[2048 + (kc * 64 + lane) * 8];
        wsl[kc] = *(const short8*)&W2B[4096 + (kc * 64 + lane) * 8];
    }
    const int rg = w & 1, pp = w >> 1;                // valid for w < 4

#pragma unroll
    for (int h = 0; h < 4; h++) {
        __syncthreads();
        if (wrow == (h >> 1)) {
#pragma unroll
            for (int ii = 0; ii < 2; ii++) {
                int i = (h & 1) * 2 + ii;
#pragma unroll
                for (int jm = 0; jm < 2; jm++) {
                    int c = 32 * wcol + 16 * jm + ml;
#pragma unroll
                    for (int r = 0; r < 4; r++) {
                        int lr = ii * 16 + quad * 4 + r;        // 0..31
                        float2 d2 = dd[rowBase + h * 32 + lr];  // < NPAD
                        float u = am[i][jm][r], v = as_[i][jm][r];
                        float m1 = u > 0.f ? u : __expf(u) - 1.f;
                        float s1 = v > 0.f ? v : 0.f;
                        float a1 = __expf(-s1);
                        float xmv = d2.x * m1 * a1;
                        float xsv = d2.y * s1 * a1 * a1;
                        u16 hh = f2bf_rne(xsv);
                        sm[lr * 136 + c]        = f2bf_rne(xmv);
                        sm[4352 + lr * 136 + c] = hh;
                        sm[8704 + lr * 136 + c] = f2bf_rne(xsv - bf2f(hh));
                    }
                }
            }
        }
        __syncthreads();
        if (w < 4) {
            floatx4 z = (floatx4){0.f, 0.f, 0.f, 0.f};
#pragma unroll
            for (int kc = 0; kc < 4; kc++) {
                if (pp == 0) {
                    short8 a = *(const short8*)&sm[(rg * 16 + ml) * 136 + kc * 32 + quad * 8];
                    z = __builtin_amdgcn_mfma_f32_16x16x32_bf16(a, wm[kc], z, 0, 0, 0);
                } else {
                    short8 a = *(const short8*)&sm[4352 + (rg * 16 + ml) * 136 + kc * 32 + quad * 8];
                    short8 b = *(const short8*)&sm[8704 + (rg * 16 + ml) * 136 + kc * 32 + quad * 8];
                    z = __builtin_amdgcn_mfma_f32_16x16x32_bf16(a, wsh[kc], z, 0, 0, 0);
                    z = __builtin_amdgcn_mfma_f32_16x16x32_bf16(a, wsl[kc], z, 0, 0, 0);
                    z = __builtin_amdgcn_mfma_f32_16x16x32_bf16(b, wsh[kc], z, 0, 0, 0);
                }
            }
            if (ml < 8) {
                int rowb = rowBase + h * 32 + rg * 16 + quad * 4;
#pragma unroll
                for (int r = 0; r < 4; r++)
                    if (rowb + r < NN) Z[(size_t)(rowb + r) * 16 + pp * 8 + ml] = z[r];
            }
        }
    }
}

// ================= CSR build =================================================
__global__ void k_scan1(const int* __restrict__ deg, int* __restrict__ bsum) {
    int t = threadIdx.x;
    int4 v = ((const int4*)deg)[blockIdx.x * 256 + t];
    __shared__ int red[256];
    red[t] = v.x + v.y + v.z + v.w;
    __syncthreads();
    for (int o = 128; o > 0; o >>= 1) {
        if (t < o) red[t] += red[t + o];
        __syncthreads();
    }
    if (t == 0) bsum[blockIdx.x] = red[0];
}

__global__ void k_scan2(const int* __restrict__ bsum, int* __restrict__ boff) {
    int t = threadIdx.x;                       // 128 threads
    __shared__ int s[128];
    int own = (t < NB) ? bsum[t] : 0;
    s[t] = own;
    __syncthreads();
    for (int o = 1; o < 128; o <<= 1) {
        int v = (t >= o) ? s[t - o] : 0;
        __syncthreads();
        s[t] += v;
        __syncthreads();
    }
    if (t < NB) boff[t] = s[t] - own;          // exclusive
}

__global__ void k_scan3(const int* __restrict__ deg, const int* __restrict__ boff,
                        int* __restrict__ ptr, int* __restrict__ cursor) {
    int t = threadIdx.x;
    int gi = blockIdx.x * 256 + t;
    int4 v = ((const int4*)deg)[gi];
    int tsum = v.x + v.y + v.z + v.w;
    __shared__ int s[256];
    s[t] = tsum;
    __syncthreads();
    for (int o = 1; o < 256; o <<= 1) {
        int pv = (t >= o) ? s[t - o] : 0;
        __syncthreads();
        s[t] += pv;
        __syncthreads();
    }
    int base = boff[blockIdx.x] + (s[t] - tsum);
    int4 e;
    e.x = base;
    e.y = base + v.x;
    e.z = e.y + v.y;
    e.w = e.z + v.z;
    ((int4*)ptr)[gi] = e;
    ((int4*)cursor)[gi] = e;
}

// payload = src index only (4 B); prime-read keeps the line in L2 so the
// random store is a write-hit instead of a 64B dirty-line HBM flush.
__global__ void k_scatter(const int* __restrict__ src, const int* __restrict__ dst,
                          int* __restrict__ cursor, int* __restrict__ pay) {
    int e = blockIdx.x * 256 + threadIdx.x;
    int d = dst[e];
    int p = atomicAdd(&cursor[d], 1);
    int pr = pay[p];                            // prime line into L2
    asm volatile("" :: "v"(pr) : "memory");     // keep load + ordering
    pay[p] = src[e];
}

// ---- agg1 + node transform fused -------------------------------------------
// wave per node i: hm = dh*sum Z[s][c], hs = dinv*sum Z[s][8+c];
// y[i] = dh[i]*elu(hm)*exp(-relu(hs)); out[i] = noise*sqrt(relu(hs)+eps)
__global__ __launch_bounds__(256) void k_aggA(const int* __restrict__ ptr,
        const int* __restrict__ pay, const float* __restrict__ Z,
        const float2* __restrict__ dd, const float* __restrict__ noise,
        float* __restrict__ y, float* __restrict__ out) {
    int wave = threadIdx.x >> 6, lane = threadIdx.x & 63;
    int i = blockIdx.x * 4 + wave;
    if (i >= NN) return;
    int er = lane >> 3, c = lane & 7;
    int s0 = ptr[i], e0 = ptr[i + 1];
    float am = 0.f, as_ = 0.f;
    int j = s0 + er;
    int sidx = (j < e0) ? pay[j] : -1;
    while (sidx >= 0) {                         // pipelined: next pay in flight
        int jn = j + 8;
        int snext = (jn < e0) ? pay[jn] : -1;
        const float* zr = Z + (size_t)sidx * 16;
        am  += zr[c];
        as_ += zr[8 + c];
        j = jn;
        sidx = snext;
    }
    am  += __shfl_xor(am, 8, 64);
    am  += __shfl_xor(am, 16, 64);
    am  += __shfl_xor(am, 32, 64);
    as_ += __shfl_xor(as_, 8, 64);
    as_ += __shfl_xor(as_, 16, 64);
    as_ += __shfl_xor(as_, 32, 64);
    if (lane < 8) {
        float2 d2 = dd[i];
        float hm = d2.x * am, hs = d2.y * as_;
        float miu2 = hm > 0.f ? hm : __expf(hm) - 1.f;
        float s2 = hs > 0.f ? hs : 0.f;
        y[i * 8 + lane]   = d2.x * miu2 * __expf(-s2);   // dh[src] folded in
        out[i * 8 + lane] = noise[i * 8 + lane] * sqrtf(s2 + 1e-8f);
    }
}

// ---- agg2: out[i][c] += dh[i] * sum y[s][c] --------------------------------
__global__ __launch_bounds__(256) void k_aggB(const int* __restrict__ ptr,
        const int* __restrict__ pay, const float* __restrict__ y,
        const float2* __restrict__ dd, float* __restrict__ out) {
    int wave = threadIdx.x >> 6, lane = threadIdx.x & 63;
    int i = blockIdx.x * 4 + wave;
    if (i >= NN) return;
    int er = lane >> 3, c = lane & 7;
    int s0 = ptr[i], e0 = ptr[i + 1];
    float acc = 0.f;
    int j = s0 + er;
    int sidx = (j < e0) ? pay[j] : -1;
    while (sidx >= 0) {
        int jn = j + 8;
        int snext = (jn < e0) ? pay[jn] : -1;
        acc += y[(size_t)sidx * 8 + c];
        j = jn;
        sidx = snext;
    }
    acc += __shfl_xor(acc, 8, 64);
    acc += __shfl_xor(acc, 16, 64);
    acc += __shfl_xor(acc, 32, 64);
    if (lane < 8) out[i * 8 + lane] += dd[i].x * acc;
}

extern "C" void kernel_launch(void* const* d_in, const int* in_sizes, int n_in,
                              void* d_out, int out_size, void* d_ws, size_t ws_size,
                              hipStream_t stream) {
    (void)in_sizes; (void)n_in; (void)out_size; (void)ws_size;
    const float* feat  = (const float*)d_in[0];
    const int*   esrc  = (const int*)d_in[1];
    const int*   edst  = (const int*)d_in[2];
    // d_in[3] (w1), d_in[4] (w2) unused: reconstructed from degrees
    const float* Wm1   = (const float*)d_in[5];
    const float* Ws1   = (const float*)d_in[6];
    const float* Wm2   = (const float*)d_in[7];
    const float* Ws2   = (const float*)d_in[8];
    const float* noise = (const float*)d_in[9];
    float* out = (float*)d_out;

    char* ws = (char*)d_ws;
    size_t off = 0;
    auto alloc = [&](size_t bytes) -> void* {
        void* p = ws + off;
        off += (bytes + 255) & ~(size_t)255;
        return p;
    };
    u16*    WhiT = (u16*)alloc((size_t)256 * 512 * 2);
    u16*    WloT = (u16*)alloc((size_t)256 * 512 * 2);
    u16*    W2B  = (u16*)alloc((size_t)6144 * 2);
    float*  Z    = (float*)alloc((size_t)NN * 16 * 4);
    float*  yb   = (float*)alloc((size_t)NN * 8 * 4);
    int*    deg  = (int*)alloc((size_t)NPAD * 4);
    float2* dd   = (float2*)alloc((size_t)NPAD * 8);
    int*    ptr  = (int*)alloc((size_t)(NPAD + 4) * 4);
    int*    cur  = (int*)alloc((size_t)NPAD * 4);
    int*    bsum = (int*)alloc(256 * 4);
    int*    boff = (int*)alloc(256 * 4);
    int*    pay  = (int*)alloc((size_t)EE * 4);

    hipMemsetAsync(deg, 0, (size_t)NPAD * 4, stream);

    // CSR build + degree weights
    k_deg    <<<EE / 256, 256, 0, stream>>>(edst, deg);
    k_dh     <<<NPAD / 256, 256, 0, stream>>>(deg, dd);
    k_scan1  <<<NB, 256, 0, stream>>>(deg, bsum);
    k_scan2  <<<1, 128, 0, stream>>>(bsum, boff);
    k_scan3  <<<NB, 256, 0, stream>>>(deg, boff, ptr, cur);
    k_scatter<<<EE / 256, 256, 0, stream>>>(esrc, edst, cur, pay);

    // dense pipeline (fused: A-split in-loop, activations + GEMM2 epilogue)
    k_split_w<<<512, 256, 0, stream>>>(Wm1, Ws1, WhiT, WloT);
    k_prep_w2<<<24, 256, 0, stream>>>(Wm2, Ws2, W2B);
    k_gemm   <<<PADM / 128, 512, 0, stream>>>(feat, WhiT, WloT, W2B, dd, Z);

    // aggregation, atomic-free (node transform fused into aggA)
    k_aggA<<<(NN + 3) / 4, 256, 0, stream>>>(ptr, pay, Z, dd, noise, yb, out);
    k_aggB<<<(NN + 3) / 4, 256, 0, stream>>>(ptr, pay, yb, dd, out);
}

// Round 5
// 568.729 us; speedup vs baseline: 1.1121x; 1.0769x over previous
//
#include <hip/hip_runtime.h>
#include <cstdint>

#define AS1 __attribute__((address_space(1)))
#define AS3 __attribute__((address_space(3)))

typedef __attribute__((ext_vector_type(8))) short short8;
typedef __attribute__((ext_vector_type(4))) float floatx4;
typedef unsigned short u16;

static constexpr int NN   = 100000;
static constexpr int FF   = 512;
static constexpr int HH   = 128;
static constexpr int EE   = 1600000;
static constexpr int PADM = 100096;   // 782 * 128
static constexpr int NPAD = 100352;   // 98 * 1024
static constexpr int NB   = 98;

__device__ __forceinline__ u16 f2bf_rne(float v) {
    uint32_t u = __builtin_bit_cast(uint32_t, v);
    u += 0x7fffu + ((u >> 16) & 1u);
    return (u16)(u >> 16);
}
__device__ __forceinline__ float bf2f(u16 h) {
    uint32_t u = ((uint32_t)h) << 16;
    return __builtin_bit_cast(float, u);
}
__device__ __forceinline__ void async16(const void* g, void* l) {
    __builtin_amdgcn_global_load_lds((AS1 const void*)g, (AS3 void*)l, 16, 0, 0);
}

// ---- W1^T = [Wm1|Ws1]^T as bf16 hi/lo, layout [n=256][k=512] ---------------
__global__ void k_split_w(const float* __restrict__ Wm1, const float* __restrict__ Ws1,
                          u16* __restrict__ whi, u16* __restrict__ wlo) {
    int t = blockIdx.x * 256 + threadIdx.x;           // t < 256*512
    int n = t >> 9, k = t & 511;
    float v = (n < HH) ? Wm1[k * HH + n] : Ws1[k * HH + (n - HH)];
    u16 h = f2bf_rne(v);
    whi[t] = h;
    wlo[t] = f2bf_rne(v - bf2f(h));
}

// ---- W2 MFMA B-fragments: plane 0 = Wm2-hi, 1 = Ws2-hi, 2 = Ws2-lo ---------
__global__ void k_prep_w2(const float* __restrict__ Wm2, const float* __restrict__ Ws2,
                          u16* __restrict__ W2B) {
    int t = blockIdx.x * 256 + threadIdx.x;           // t < 6144
    int j = t & 7, l = (t >> 3) & 63, kc = (t >> 9) & 3, p = t >> 11;
    int n = l & 15, quad = l >> 4;
    int k = kc * 32 + quad * 8 + j;
    float v = 0.f;
    if (n < 8) {
        float wv = (p == 0) ? Wm2[k * 8 + n] : Ws2[k * 8 + n];
        v = (p == 2) ? (wv - bf2f(f2bf_rne(wv))) : wv;
    }
    W2B[t] = f2bf_rne(v);
}

// ---- degree + per-edge rank (one atomic pass feeds BOTH deg and scatter) ---
__global__ void k_deg(const int* __restrict__ dst, int* __restrict__ deg,
                      int* __restrict__ rank) {
    int e = blockIdx.x * 256 + threadIdx.x;
    rank[e] = atomicAdd(&deg[dst[e]], 1);
}

// ---- fused GEMM1 + activations + GEMM2 -> Z[node][16] ----------------------
// block = 128 rows x 256 cols, 512 threads / 8 waves.  (round-0 structure:
// best measured variant, 134.8 us.)
__global__ __launch_bounds__(512, 4) void k_gemm(
        const float* __restrict__ A,
        const u16* __restrict__ BhiG, const u16* __restrict__ BloG,
        const u16* __restrict__ W2B, const float2* __restrict__ dd,
        float* __restrict__ Z) {
    __shared__ u16 sm[24576];   // 48 KB
    // K-loop: Ahi[0,4096) Alo[4096,8192) Bhi[8192,16384) Blo[16384,24576)
    // epi:    xm[0,4352)  xs_hi[4352,8704)  xs_lo[8704,13056)  (stride 136)
    const int tid = threadIdx.x;
    const int w = tid >> 6, lane = tid & 63;
    const int ml = lane & 15, quad = lane >> 4;
    const int wrow = w & 1, wcol = w >> 1;
    const int rowBase = blockIdx.x * 128;

    floatx4 am[4][2], as_[4][2];
#pragma unroll
    for (int i = 0; i < 4; i++)
#pragma unroll
        for (int j = 0; j < 2; j++) {
            am[i][j]  = (floatx4){0.f, 0.f, 0.f, 0.f};
            as_[i][j] = (floatx4){0.f, 0.f, 0.f, 0.f};
        }

    const int r0 = tid >> 2, ko = (tid & 3) * 8;      // r0: 0..127
    const int arow = min(rowBase + r0, NN - 1);       // clamp; pad rows discarded
    const float* gA = A + (size_t)arow * FF + ko;
    const u16* gBh = BhiG + (size_t)r0 * FF + ko;          // rows 0..127
    const u16* gBl = BloG + (size_t)(128 + r0) * FF + ko;  // sigma rows 128..255

    const int aoff = (wrow * 64 + ml) * 32 + quad * 8;
    const int bmo  = 8192  + (32 * wcol + ml) * 32 + quad * 8;
    const int bso  = 12288 + (32 * wcol + ml) * 32 + quad * 8;
    const int blo_ = 16384 + (32 * wcol + ml) * 32 + quad * 8;

    for (int kt = 0; kt < FF; kt += 32) {
        __syncthreads();
        async16(gBh + kt,                      &sm[8192  + tid * 8]);
        async16(gBh + (size_t)128 * FF + kt,   &sm[12288 + tid * 8]);
        async16(gBl + kt,                      &sm[16384 + tid * 8]);
        {
            const float4* pA = (const float4*)(gA + kt);
            float4 x0 = pA[0], x1 = pA[1];
            float xv[8] = {x0.x, x0.y, x0.z, x0.w, x1.x, x1.y, x1.z, x1.w};
            short8 hv, lv;
#pragma unroll
            for (int q = 0; q < 8; q++) {
                u16 hh = f2bf_rne(xv[q]);
                hv[q] = (short)hh;
                lv[q] = (short)f2bf_rne(xv[q] - bf2f(hh));
            }
            *(short8*)&sm[tid * 8] = hv;
            *(short8*)&sm[4096 + tid * 8] = lv;
        }
        __syncthreads();

        short8 ah[4], al[4];
#pragma unroll
        for (int i = 0; i < 4; i++) ah[i] = *(const short8*)&sm[aoff + i * 512];
#pragma unroll
        for (int i = 0; i < 4; i++) al[i] = *(const short8*)&sm[4096 + aoff + i * 512];
#pragma unroll
        for (int jm = 0; jm < 2; jm++) {
            short8 b = *(const short8*)&sm[bmo + jm * 512];
#pragma unroll
            for (int i = 0; i < 4; i++)
                am[i][jm] = __builtin_amdgcn_mfma_f32_16x16x32_bf16(ah[i], b, am[i][jm], 0, 0, 0);
        }
#pragma unroll
        for (int js = 0; js < 2; js++) {
            short8 bh = *(const short8*)&sm[bso + js * 512];
            short8 bl = *(const short8*)&sm[blo_ + js * 512];
#pragma unroll
            for (int i = 0; i < 4; i++) {
                floatx4 c = as_[i][js];
                c = __builtin_amdgcn_mfma_f32_16x16x32_bf16(ah[i], bh, c, 0, 0, 0);
                c = __builtin_amdgcn_mfma_f32_16x16x32_bf16(ah[i], bl, c, 0, 0, 0);
                c = __builtin_amdgcn_mfma_f32_16x16x32_bf16(al[i], bh, c, 0, 0, 0);
                as_[i][js] = c;
            }
        }
    }

    // ---- epilogue: 4 chunks of 32 rows -------------------------------------
    short8 wm[4], wsh[4], wsl[4];
#pragma unroll
    for (int kc = 0; kc < 4; kc++) {
        wm[kc]  = *(const short8*)&W2B[(kc * 64 + lane) * 8];
        wsh[kc] = *(const short8*)&W2B[2048 + (kc * 64 + lane) * 8];
        wsl[kc] = *(const short8*)&W2B[4096 + (kc * 64 + lane) * 8];
    }
    const int rg = w & 1, pp = w >> 1;                // valid for w < 4

#pragma unroll
    for (int h = 0; h < 4; h++) {
        __syncthreads();
        if (wrow == (h >> 1)) {
#pragma unroll
            for (int ii = 0; ii < 2; ii++) {
                int i = (h & 1) * 2 + ii;
#pragma unroll
                for (int jm = 0; jm < 2; jm++) {
                    int c = 32 * wcol + 16 * jm + ml;
#pragma unroll
                    for (int r = 0; r < 4; r++) {
                        int lr = ii * 16 + quad * 4 + r;        // 0..31
                        float2 d2 = dd[rowBase + h * 32 + lr];  // < NPAD
                        float u = am[i][jm][r], v = as_[i][jm][r];
                        float m1 = u > 0.f ? u : __expf(u) - 1.f;
                        float s1 = v > 0.f ? v : 0.f;
                        float a1 = __expf(-s1);
                        float xmv = d2.x * m1 * a1;
                        float xsv = d2.y * s1 * a1 * a1;
                        u16 hh = f2bf_rne(xsv);
                        sm[lr * 136 + c]        = f2bf_rne(xmv);
                        sm[4352 + lr * 136 + c] = hh;
                        sm[8704 + lr * 136 + c] = f2bf_rne(xsv - bf2f(hh));
                    }
                }
            }
        }
        __syncthreads();
        if (w < 4) {
            floatx4 z = (floatx4){0.f, 0.f, 0.f, 0.f};
#pragma unroll
            for (int kc = 0; kc < 4; kc++) {
                if (pp == 0) {
                    short8 a = *(const short8*)&sm[(rg * 16 + ml) * 136 + kc * 32 + quad * 8];
                    z = __builtin_amdgcn_mfma_f32_16x16x32_bf16(a, wm[kc], z, 0, 0, 0);
                } else {
                    short8 a = *(const short8*)&sm[4352 + (rg * 16 + ml) * 136 + kc * 32 + quad * 8];
                    short8 b = *(const short8*)&sm[8704 + (rg * 16 + ml) * 136 + kc * 32 + quad * 8];
                    z = __builtin_amdgcn_mfma_f32_16x16x32_bf16(a, wsh[kc], z, 0, 0, 0);
                    z = __builtin_amdgcn_mfma_f32_16x16x32_bf16(a, wsl[kc], z, 0, 0, 0);
                    z = __builtin_amdgcn_mfma_f32_16x16x32_bf16(b, wsh[kc], z, 0, 0, 0);
                }
            }
            if (ml < 8) {
                int rowb = rowBase + h * 32 + rg * 16 + quad * 4;
#pragma unroll
                for (int r = 0; r < 4; r++)
                    if (rowb + r < NN) Z[(size_t)(rowb + r) * 16 + pp * 8 + ml] = z[r];
            }
        }
    }
}

// ================= CSR build =================================================
__global__ void k_scan1(const int* __restrict__ deg, int* __restrict__ bsum) {
    int t = threadIdx.x;
    int4 v = ((const int4*)deg)[blockIdx.x * 256 + t];
    __shared__ int red[256];
    red[t] = v.x + v.y + v.z + v.w;
    __syncthreads();
    for (int o = 128; o > 0; o >>= 1) {
        if (t < o) red[t] += red[t + o];
        __syncthreads();
    }
    if (t == 0) bsum[blockIdx.x] = red[0];
}

__global__ void k_scan2(const int* __restrict__ bsum, int* __restrict__ boff) {
    int t = threadIdx.x;                       // 128 threads
    __shared__ int s[128];
    int own = (t < NB) ? bsum[t] : 0;
    s[t] = own;
    __syncthreads();
    for (int o = 1; o < 128; o <<= 1) {
        int v = (t >= o) ? s[t - o] : 0;
        __syncthreads();
        s[t] += v;
        __syncthreads();
    }
    if (t < NB) boff[t] = s[t] - own;          // exclusive
}

// scan3 also emits dd (deg values are already in registers here; k_dh removed)
__global__ void k_scan3(const int* __restrict__ deg, const int* __restrict__ boff,
                        int* __restrict__ ptr, float2* __restrict__ dd) {
    int t = threadIdx.x;
    int gi = blockIdx.x * 256 + t;
    int4 v = ((const int4*)deg)[gi];
    int tsum = v.x + v.y + v.z + v.w;
    __shared__ int s[256];
    s[t] = tsum;
    __syncthreads();
    for (int o = 1; o < 256; o <<= 1) {
        int pv = (t >= o) ? s[t - o] : 0;
        __syncthreads();
        s[t] += pv;
        __syncthreads();
    }
    int base = boff[blockIdx.x] + (s[t] - tsum);
    int4 e;
    e.x = base;
    e.y = base + v.x;
    e.z = e.y + v.y;
    e.w = e.z + v.z;
    ((int4*)ptr)[gi] = e;
    float d0 = (float)max(v.x, 1), d1 = (float)max(v.y, 1);
    float d2 = (float)max(v.z, 1), d3 = (float)max(v.w, 1);
    float4 da = make_float4(1.f / sqrtf(d0), 1.f / d0, 1.f / sqrtf(d1), 1.f / d1);
    float4 db = make_float4(1.f / sqrtf(d2), 1.f / d2, 1.f / sqrtf(d3), 1.f / d3);
    ((float4*)dd)[gi * 2]     = da;
    ((float4*)dd)[gi * 2 + 1] = db;
}

// atomic-free scatter: p = ptr[dst] + rank (rank captured during k_deg's
// atomic).  prime-read keeps the line in L2 so the random 4B store is a
// write-hit instead of a 64B dirty-line HBM flush.
__global__ void k_scatter(const int* __restrict__ src, const int* __restrict__ dst,
                          const int* __restrict__ rank, const int* __restrict__ ptr,
                          int* __restrict__ pay) {
    int e = blockIdx.x * 256 + threadIdx.x;
    int d = dst[e];
    int p = ptr[d] + rank[e];
    int pr = pay[p];                            // prime line into L2
    asm volatile("" :: "v"(pr) : "memory");     // keep load + ordering
    pay[p] = src[e];
}

// ---- agg1 + node transform fused -------------------------------------------
// wave per node i; 4 lanes per edge, float4 gathers (full 64B Z row per edge,
// 16 edges in flight per iteration).  er = lane>>2, q = lane&3:
// q=0,1 -> miu cols 0-7; q=2,3 -> sigma cols 8-15.
__global__ __launch_bounds__(256) void k_aggA(const int* __restrict__ ptr,
        const int* __restrict__ pay, const float* __restrict__ Z,
        const float2* __restrict__ dd, const float* __restrict__ noise,
        float* __restrict__ y, float* __restrict__ out) {
    int wave = threadIdx.x >> 6, lane = threadIdx.x & 63;
    int i = blockIdx.x * 4 + wave;
    if (i >= NN) return;
    int er = lane >> 2, q = lane & 3;
    int s0 = ptr[i], e0 = ptr[i + 1];
    floatx4 acc = (floatx4){0.f, 0.f, 0.f, 0.f};
    int j = s0 + er;
    int sidx = (j < e0) ? pay[j] : -1;
    while (sidx >= 0) {                         // pipelined: next pay in flight
        int jn = j + 16;
        int snext = (jn < e0) ? pay[jn] : -1;
        floatx4 zv = *(const floatx4*)(Z + (size_t)sidx * 16 + q * 4);
        acc += zv;
        j = jn;
        sidx = snext;
    }
#pragma unroll
    for (int m = 4; m <= 32; m <<= 1) {
#pragma unroll
        for (int k = 0; k < 4; k++) acc[k] += __shfl_xor(acc[k], m, 64);
    }
    floatx4 oth;                                // sigma partner (q^2)
#pragma unroll
    for (int k = 0; k < 4; k++) oth[k] = __shfl_xor(acc[k], 2, 64);
    if (lane < 2) {                             // er==0, q in {0,1}
        float2 d2 = dd[i];
        floatx4 nv = *(const floatx4*)(noise + (size_t)i * 8 + q * 4);
        floatx4 yv, ov;
#pragma unroll
        for (int k = 0; k < 4; k++) {
            float hm = d2.x * acc[k];
            float hs = d2.y * oth[k];
            float miu2 = hm > 0.f ? hm : __expf(hm) - 1.f;
            float s2 = hs > 0.f ? hs : 0.f;
            yv[k] = d2.x * miu2 * __expf(-s2);  // dh[src] folded in
            ov[k] = nv[k] * sqrtf(s2 + 1e-8f);
        }
        *(floatx4*)(y + (size_t)i * 8 + q * 4)   = yv;
        *(floatx4*)(out + (size_t)i * 8 + q * 4) = ov;
    }
}

// ---- agg2: out[i][c] += dh[i] * sum y[s][c] --------------------------------
// 2 lanes per edge, float4 gathers (32 edges in flight per iteration).
__global__ __launch_bounds__(256) void k_aggB(const int* __restrict__ ptr,
        const int* __restrict__ pay, const float* __restrict__ y,
        const float2* __restrict__ dd, float* __restrict__ out) {
    int wave = threadIdx.x >> 6, lane = threadIdx.x & 63;
    int i = blockIdx.x * 4 + wave;
    if (i >= NN) return;
    int er = lane >> 1, q = lane & 1;
    int s0 = ptr[i], e0 = ptr[i + 1];
    floatx4 acc = (floatx4){0.f, 0.f, 0.f, 0.f};
    int j = s0 + er;
    int sidx = (j < e0) ? pay[j] : -1;
    while (sidx >= 0) {
        int jn = j + 32;
        int snext = (jn < e0) ? pay[jn] : -1;
        floatx4 yv = *(const floatx4*)(y + (size_t)sidx * 8 + q * 4);
        acc += yv;
        j = jn;
        sidx = snext;
    }
#pragma unroll
    for (int m = 2; m <= 32; m <<= 1) {
#pragma unroll
        for (int k = 0; k < 4; k++) acc[k] += __shfl_xor(acc[k], m, 64);
    }
    if (lane < 2) {                             // er==0, q in {0,1}
        float dh = dd[i].x;
        float* po = out + (size_t)i * 8 + q * 4;
        floatx4 o = *(floatx4*)po;
#pragma unroll
        for (int k = 0; k < 4; k++) o[k] += dh * acc[k];
        *(floatx4*)po = o;
    }
}

extern "C" void kernel_launch(void* const* d_in, const int* in_sizes, int n_in,
                              void* d_out, int out_size, void* d_ws, size_t ws_size,
                              hipStream_t stream) {
    (void)in_sizes; (void)n_in; (void)out_size; (void)ws_size;
    const float* feat  = (const float*)d_in[0];
    const int*   esrc  = (const int*)d_in[1];
    const int*   edst  = (const int*)d_in[2];
    // d_in[3] (w1), d_in[4] (w2) unused: reconstructed from degrees
    const float* Wm1   = (const float*)d_in[5];
    const float* Ws1   = (const float*)d_in[6];
    const float* Wm2   = (const float*)d_in[7];
    const float* Ws2   = (const float*)d_in[8];
    const float* noise = (const float*)d_in[9];
    float* out = (float*)d_out;

    char* ws = (char*)d_ws;
    size_t off = 0;
    auto alloc = [&](size_t bytes) -> void* {
        void* p = ws + off;
        off += (bytes + 255) & ~(size_t)255;
        return p;
    };
    u16*    WhiT = (u16*)alloc((size_t)256 * 512 * 2);
    u16*    WloT = (u16*)alloc((size_t)256 * 512 * 2);
    u16*    W2B  = (u16*)alloc((size_t)6144 * 2);
    float*  Z    = (float*)alloc((size_t)NN * 16 * 4);
    float*  yb   = (float*)alloc((size_t)NN * 8 * 4);
    int*    deg  = (int*)alloc((size_t)NPAD * 4);
    float2* dd   = (float2*)alloc((size_t)NPAD * 8);
    int*    ptr  = (int*)alloc((size_t)(NPAD + 4) * 4);
    int*    bsum = (int*)alloc(256 * 4);
    int*    boff = (int*)alloc(256 * 4);
    int*    pay  = (int*)alloc((size_t)EE * 4);
    // rank aliases Z: consumed by k_scatter strictly before k_gemm writes Z
    int*    rank = (int*)Z;                    // EE*4 = 6.4 MB == NN*16*4

    hipMemsetAsync(deg, 0, (size_t)NPAD * 4, stream);

    // CSR build + degree weights (single atomic pass; scatter is atomic-free)
    k_deg    <<<EE / 256, 256, 0, stream>>>(edst, deg, rank);
    k_scan1  <<<NB, 256, 0, stream>>>(deg, bsum);
    k_scan2  <<<1, 128, 0, stream>>>(bsum, boff);
    k_scan3  <<<NB, 256, 0, stream>>>(deg, boff, ptr, dd);
    k_scatter<<<EE / 256, 256, 0, stream>>>(esrc, edst, rank, ptr, pay);

    // dense pipeline (fused: A-split in-loop, activations + GEMM2 epilogue)
    k_split_w<<<512, 256, 0, stream>>>(Wm1, Ws1, WhiT, WloT);
    k_prep_w2<<<24, 256, 0, stream>>>(Wm2, Ws2, W2B);
    k_gemm   <<<PADM / 128, 512, 0, stream>>>(feat, WhiT, WloT, W2B, dd, Z);

    // aggregation, atomic-free (node transform fused into aggA)
    k_aggA<<<(NN + 3) / 4, 256, 0, stream>>>(ptr, pay, Z, dd, noise, yb, out);
    k_aggB<<<(NN + 3) / 4, 256, 0, stream>>>(ptr, pay, yb, dd, out);
}